// Round 1
// baseline (230.539 us; speedup 1.0000x reference)
//
#include <hip/hip_runtime.h>

#define DMODEL 1024
#define NHEADS 16
#define DHEAD  64
#define RANK   16
#define BATCH  4
#define SEQ    1024
#define MTOT   (BATCH*SEQ)   // 4096

typedef __bf16 bf16;
typedef __bf16 bf16x8 __attribute__((ext_vector_type(8)));
typedef __bf16 bf16x4 __attribute__((ext_vector_type(4)));
typedef float  f32x4  __attribute__((ext_vector_type(4)));

// Byte-offset swizzle for LDS tiles with 128B rows: XOR the 16B-slot index
// with (row&7) -> 16 lanes reading the same slot of 16 consecutive rows hit
// 8 distinct slots (2-way aliasing = free per m136).
__device__ __forceinline__ int swz128(int row, int byte_in_row) {
  int slot = byte_in_row >> 4;
  return row * 128 + (((slot ^ (row & 7)) << 4) | (byte_in_row & 15));
}

// ---------------- Weff = W + 2 * (A@B)^T  (stored [n][k], bf16) -------------
__global__ void prep_weff_kernel(const float* __restrict__ W, const float* __restrict__ A,
                                 const float* __restrict__ Bm, bf16* __restrict__ out) {
  const int n = blockIdx.x;
  __shared__ float bsc[RANK];
  if (threadIdx.x < RANK) bsc[threadIdx.x] = Bm[threadIdx.x * DMODEL + n] * 2.0f;
  __syncthreads();
  float br[RANK];
#pragma unroll
  for (int r = 0; r < RANK; ++r) br[r] = bsc[r];
  for (int k0 = 0; k0 < DMODEL; k0 += 256) {
    int k = k0 + threadIdx.x;
    float acc = W[n * DMODEL + k];
    const float4* arow = (const float4*)(A + k * RANK);
#pragma unroll
    for (int r4 = 0; r4 < 4; ++r4) {
      float4 a = arow[r4];
      acc += a.x*br[r4*4+0] + a.y*br[r4*4+1] + a.z*br[r4*4+2] + a.w*br[r4*4+3];
    }
    out[n * DMODEL + k] = (bf16)acc;
  }
}

__global__ void cast_x_kernel(const float* __restrict__ x, bf16* __restrict__ xb) {
  int i = (blockIdx.x * blockDim.x + threadIdx.x) * 4;
  float4 v = *(const float4*)(x + i);
  bf16x4 o = { (bf16)v.x, (bf16)v.y, (bf16)v.z, (bf16)v.w };
  *(bf16x4*)(xb + i) = o;
}

// ---------------- GEMM: Y[m][n] = sum_k A[m][k]*Weff[n][k] + bias[n] --------
// MODE 0: scatter bf16 to [b][h][s][d]   (Q, K)
// MODE 2: scatter bf16 to [b][h][d][s]   (V transposed)
// MODE 3: fp32 out = Y + resid (residual), row-major [m][n]
template<int MODE>
__global__ __launch_bounds__(256) void gemm_kernel(
    const bf16* __restrict__ Ain, const bf16* __restrict__ Bin,
    const float* __restrict__ bias, bf16* __restrict__ outb,
    float* __restrict__ outf, const float* __restrict__ resid)
{
  __shared__ __align__(16) char sA[128 * 128];  // 128 rows x 64 bf16 (128B)
  __shared__ __align__(16) char sB[128 * 128];
  const int tid = threadIdx.x;
  const int w = tid >> 6, lane = tid & 63;
  const int m0 = blockIdx.y * 128, n0 = blockIdx.x * 128;
  const int wm = (w & 1) * 64, wn = (w >> 1) * 64;
  f32x4 acc[4][4] = {};

  for (int kt = 0; kt < DMODEL / 64; ++kt) {
    const int kbase = kt * 64;
#pragma unroll
    for (int i = 0; i < 4; ++i) {
      int row = i * 32 + (tid >> 3), slot = tid & 7;
      uint4 va = *(const uint4*)(Ain + (size_t)(m0 + row) * DMODEL + kbase + slot * 8);
      *(uint4*)(sA + swz128(row, slot * 16)) = va;
      uint4 vb = *(const uint4*)(Bin + (size_t)(n0 + row) * DMODEL + kbase + slot * 8);
      *(uint4*)(sB + swz128(row, slot * 16)) = vb;
    }
    __syncthreads();
#pragma unroll
    for (int ks = 0; ks < 2; ++ks) {
      bf16x8 af[4], bfg[4];
#pragma unroll
      for (int mi = 0; mi < 4; ++mi)
        af[mi] = *(const bf16x8*)(sA + swz128(wm + mi*16 + (lane & 15), ks*64 + (lane >> 4)*16));
#pragma unroll
      for (int ni = 0; ni < 4; ++ni)
        bfg[ni] = *(const bf16x8*)(sB + swz128(wn + ni*16 + (lane & 15), ks*64 + (lane >> 4)*16));
#pragma unroll
      for (int mi = 0; mi < 4; ++mi)
#pragma unroll
        for (int ni = 0; ni < 4; ++ni)
          acc[mi][ni] = __builtin_amdgcn_mfma_f32_16x16x32_bf16(af[mi], bfg[ni], acc[mi][ni], 0, 0, 0);
    }
    __syncthreads();
  }

#pragma unroll
  for (int mi = 0; mi < 4; ++mi) {
#pragma unroll
    for (int ni = 0; ni < 4; ++ni) {
      int col = n0 + wn + ni * 16 + (lane & 15);
      float bcol = bias[col];
#pragma unroll
      for (int r = 0; r < 4; ++r) {
        int row = m0 + wm + mi * 16 + (lane >> 4) * 4 + r;
        float v = acc[mi][ni][r] + bcol;
        if (MODE == 0) {
          int b = row >> 10, s = row & 1023, h = col >> 6, d = col & 63;
          outb[(size_t)((b * NHEADS + h) * SEQ + s) * DHEAD + d] = (bf16)v;
        } else if (MODE == 2) {
          int b = row >> 10, s = row & 1023, h = col >> 6, d = col & 63;
          outb[(size_t)((b * NHEADS + h) * DHEAD + d) * SEQ + s] = (bf16)v;
        } else {
          outf[(size_t)row * DMODEL + col] = v + resid[(size_t)row * DMODEL + col];
        }
      }
    }
  }
}

// ---------------- flash attention fwd, saves (m,l) stats --------------------
__global__ __launch_bounds__(256) void flash_kernel(
    const bf16* __restrict__ Qb, const bf16* __restrict__ Kb, const bf16* __restrict__ Vt,
    bf16* __restrict__ ctx, float* __restrict__ mstat, float* __restrict__ lstat)
{
  __shared__ __align__(16) char sK[64 * 128];       // rows=key, cols=d
  __shared__ __align__(16) char sV[64 * 128];       // rows=d,   cols=key
  __shared__ __align__(16) char sP[4 * 16 * 128];   // per-wave 16 x 64 bf16
  const int tid = threadIdx.x, w = tid >> 6, lane = tid & 63;
  const int bh = blockIdx.y;
  const int q0 = blockIdx.x * 64;
  const bf16* Qbase = Qb + (size_t)bh * SEQ * DHEAD;
  const bf16* Kbase = Kb + (size_t)bh * SEQ * DHEAD;
  const bf16* Vbase = Vt + (size_t)bh * DHEAD * SEQ;
  const int qw = q0 + w * 16;

  bf16x8 aq[2];
#pragma unroll
  for (int ks = 0; ks < 2; ++ks)
    aq[ks] = *(const bf16x8*)(Qbase + (size_t)(qw + (lane & 15)) * DHEAD + ks * 32 + (lane >> 4) * 8);

  f32x4 cacc[4] = {};
  float mrow[4], lrow[4];
#pragma unroll
  for (int r = 0; r < 4; ++r) { mrow[r] = -1e30f; lrow[r] = 0.0f; }

  for (int kt = 0; kt < SEQ / 64; ++kt) {
    const int k0 = kt * 64;
#pragma unroll
    for (int i = 0; i < 2; ++i) {
      int idx = i * 256 + tid, row = idx >> 3, slot = idx & 7;
      uint4 vk = *(const uint4*)(Kbase + (size_t)(k0 + row) * DHEAD + slot * 8);
      *(uint4*)(sK + swz128(row, slot * 16)) = vk;
      uint4 vv = *(const uint4*)(Vbase + (size_t)row * SEQ + k0 + slot * 8);
      *(uint4*)(sV + swz128(row, slot * 16)) = vv;
    }
    __syncthreads();

    f32x4 sc[4] = {};
#pragma unroll
    for (int ks = 0; ks < 2; ++ks)
#pragma unroll
      for (int ni = 0; ni < 4; ++ni) {
        bf16x8 bk = *(const bf16x8*)(sK + swz128(ni*16 + (lane & 15), ks*64 + (lane >> 4)*16));
        sc[ni] = __builtin_amdgcn_mfma_f32_16x16x32_bf16(aq[ks], bk, sc[ni], 0, 0, 0);
      }
#pragma unroll
    for (int ni = 0; ni < 4; ++ni)
#pragma unroll
      for (int r = 0; r < 4; ++r) sc[ni][r] *= 0.125f;

#pragma unroll
    for (int r = 0; r < 4; ++r) {
      float mx = fmaxf(fmaxf(sc[0][r], sc[1][r]), fmaxf(sc[2][r], sc[3][r]));
#pragma unroll
      for (int off = 1; off < 16; off <<= 1) mx = fmaxf(mx, __shfl_xor(mx, off));
      float mnew = fmaxf(mrow[r], mx);
      float al = __expf(mrow[r] - mnew);
      float rs = 0.0f;
#pragma unroll
      for (int ni = 0; ni < 4; ++ni) {
        float p = __expf(sc[ni][r] - mnew);
        sc[ni][r] = p;
        rs += p;
      }
#pragma unroll
      for (int off = 1; off < 16; off <<= 1) rs += __shfl_xor(rs, off);
      lrow[r] = lrow[r] * al + rs;
      mrow[r] = mnew;
#pragma unroll
      for (int ni = 0; ni < 4; ++ni) cacc[ni][r] *= al;
    }

    // P (C-layout) -> per-wave LDS, then read back as A-fragments
    char* sPw = sP + w * 2048;
#pragma unroll
    for (int ni = 0; ni < 4; ++ni)
#pragma unroll
      for (int r = 0; r < 4; ++r) {
        int prow = (lane >> 4) * 4 + r;
        int pcolb = ni * 32 + (lane & 15) * 2;
        *(bf16*)(sPw + swz128(prow, pcolb)) = (bf16)sc[ni][r];
      }
    asm volatile("s_waitcnt lgkmcnt(0)" ::: "memory");  // own-wave visibility
#pragma unroll
    for (int ks = 0; ks < 2; ++ks) {
      bf16x8 ap = *(const bf16x8*)(sPw + swz128(lane & 15, ks*64 + (lane >> 4)*16));
#pragma unroll
      for (int ni = 0; ni < 4; ++ni) {
        bf16x8 bv = *(const bf16x8*)(sV + swz128(ni*16 + (lane & 15), ks*64 + (lane >> 4)*16));
        cacc[ni] = __builtin_amdgcn_mfma_f32_16x16x32_bf16(ap, bv, cacc[ni], 0, 0, 0);
      }
    }
    __syncthreads();
  }

  const int b = bh >> 4, hh = bh & 15;
#pragma unroll
  for (int r = 0; r < 4; ++r) {
    float inv = 1.0f / lrow[r];
    int qrow = qw + (lane >> 4) * 4 + r;
#pragma unroll
    for (int ni = 0; ni < 4; ++ni) {
      int d = ni * 16 + (lane & 15);
      ctx[(size_t)(b * SEQ + qrow) * DMODEL + hh * DHEAD + d] = (bf16)(cacc[ni][r] * inv);
    }
    if ((lane & 15) == 0) {
      mstat[(size_t)bh * SEQ + qrow] = mrow[r];
      lstat[(size_t)bh * SEQ + qrow] = lrow[r];
    }
  }
}

// ---------------- attn.mean over heads: recompute scores with saved stats ---
__global__ __launch_bounds__(256) void mean_kernel(
    const bf16* __restrict__ Qb, const bf16* __restrict__ Kb,
    const float* __restrict__ mstat, const float* __restrict__ lstat,
    float* __restrict__ out2)
{
  __shared__ __align__(16) char sK[64 * 128];
  const int tid = threadIdx.x, w = tid >> 6, lane = tid & 63;
  const int b = blockIdx.z;
  const int q0 = blockIdx.x * 64, k0 = blockIdx.y * 64;
  const int qw = q0 + w * 16;
  f32x4 macc[4] = {};
  for (int h = 0; h < NHEADS; ++h) {
    int bh = b * NHEADS + h;
    const bf16* Qbase = Qb + (size_t)bh * SEQ * DHEAD;
    const bf16* Kbase = Kb + (size_t)bh * SEQ * DHEAD;
#pragma unroll
    for (int i = 0; i < 2; ++i) {
      int idx = i * 256 + tid, row = idx >> 3, slot = idx & 7;
      uint4 vk = *(const uint4*)(Kbase + (size_t)(k0 + row) * DHEAD + slot * 8);
      *(uint4*)(sK + swz128(row, slot * 16)) = vk;
    }
    __syncthreads();
    bf16x8 aq0 = *(const bf16x8*)(Qbase + (size_t)(qw + (lane & 15)) * DHEAD + (lane >> 4) * 8);
    bf16x8 aq1 = *(const bf16x8*)(Qbase + (size_t)(qw + (lane & 15)) * DHEAD + 32 + (lane >> 4) * 8);
    f32x4 sc[4] = {};
#pragma unroll
    for (int ni = 0; ni < 4; ++ni) {
      bf16x8 bk0 = *(const bf16x8*)(sK + swz128(ni*16 + (lane & 15), (lane >> 4)*16));
      sc[ni] = __builtin_amdgcn_mfma_f32_16x16x32_bf16(aq0, bk0, sc[ni], 0, 0, 0);
      bf16x8 bk1 = *(const bf16x8*)(sK + swz128(ni*16 + (lane & 15), 64 + (lane >> 4)*16));
      sc[ni] = __builtin_amdgcn_mfma_f32_16x16x32_bf16(aq1, bk1, sc[ni], 0, 0, 0);
    }
    float msc[4], lsc[4];
#pragma unroll
    for (int r = 0; r < 4; ++r) {
      int qrow = qw + (lane >> 4) * 4 + r;
      msc[r] = mstat[(size_t)bh * SEQ + qrow];
      lsc[r] = 0.0625f / lstat[(size_t)bh * SEQ + qrow];   // 1/(16*l)
    }
#pragma unroll
    for (int ni = 0; ni < 4; ++ni)
#pragma unroll
      for (int r = 0; r < 4; ++r)
        macc[ni][r] += __expf(sc[ni][r] * 0.125f - msc[r]) * lsc[r];
    __syncthreads();
  }
#pragma unroll
  for (int r = 0; r < 4; ++r) {
    int qrow = qw + (lane >> 4) * 4 + r;
#pragma unroll
    for (int ni = 0; ni < 4; ++ni)
      out2[(size_t)(b * SEQ + qrow) * SEQ + k0 + ni * 16 + (lane & 15)] = macc[ni][r];
  }
}

// ---------------- residual LayerNorm (in-place on fp32 rows) ----------------
__global__ __launch_bounds__(256) void ln_kernel(
    float* __restrict__ hb, const float* __restrict__ g,
    const float* __restrict__ bvec, float* __restrict__ out)
{
  const int row = blockIdx.x, t = threadIdx.x;
  float4 v = *(const float4*)(hb + (size_t)row * DMODEL + t * 4);
  float s = v.x + v.y + v.z + v.w;
  float s2 = v.x*v.x + v.y*v.y + v.z*v.z + v.w*v.w;
#pragma unroll
  for (int off = 32; off >= 1; off >>= 1) {
    s  += __shfl_down(s, off);
    s2 += __shfl_down(s2, off);
  }
  __shared__ float red[8];
  const int w = t >> 6;
  if ((t & 63) == 0) { red[w] = s; red[4 + w] = s2; }
  __syncthreads();
  if (t == 0) {
    red[0] = red[0] + red[1] + red[2] + red[3];
    red[4] = red[4] + red[5] + red[6] + red[7];
  }
  __syncthreads();
  float mu = red[0] * (1.0f / DMODEL);
  float var = red[4] * (1.0f / DMODEL) - mu * mu;
  float rs = rsqrtf(var + 1e-5f);
  float4 gv = *(const float4*)(g + t * 4);
  float4 bv = *(const float4*)(bvec + t * 4);
  float4 o;
  o.x = (v.x - mu) * rs * gv.x + bv.x;
  o.y = (v.y - mu) * rs * gv.y + bv.y;
  o.z = (v.z - mu) * rs * gv.z + bv.z;
  o.w = (v.w - mu) * rs * gv.w + bv.w;
  *(float4*)(out + (size_t)row * DMODEL + t * 4) = o;
}

extern "C" void kernel_launch(void* const* d_in, const int* in_sizes, int n_in,
                              void* d_out, int out_size, void* d_ws, size_t ws_size,
                              hipStream_t stream) {
  (void)in_sizes; (void)n_in; (void)out_size; (void)ws_size;
  const float* x = (const float*)d_in[0];
  const float* w_[4]  = {(const float*)d_in[1],  (const float*)d_in[5],
                         (const float*)d_in[9],  (const float*)d_in[13]};
  const float* b_[4]  = {(const float*)d_in[2],  (const float*)d_in[6],
                         (const float*)d_in[10], (const float*)d_in[14]};
  const float* A_[4]  = {(const float*)d_in[3],  (const float*)d_in[7],
                         (const float*)d_in[11], (const float*)d_in[15]};
  const float* Bm_[4] = {(const float*)d_in[4],  (const float*)d_in[8],
                         (const float*)d_in[12], (const float*)d_in[16]};
  const float* lng = (const float*)d_in[17];
  const float* lnb = (const float*)d_in[18];

  char* ws = (char*)d_ws;
  bf16* xb    = (bf16*)(ws);                         // 8MB, reused as ctx later
  bf16* weff  = (bf16*)(ws + (8u  << 20));           // 4 x 2MB
  bf16* Qb    = (bf16*)(ws + (16u << 20));           // 8MB [b][h][s][d]
  bf16* Kb    = (bf16*)(ws + (24u << 20));           // 8MB [b][h][s][d]
  bf16* Vt    = (bf16*)(ws + (32u << 20));           // 8MB [b][h][d][s]
  float* mstat = (float*)(ws + (40u << 20));         // 256KB
  float* lstat = (float*)(ws + (40u << 20) + (256u << 10));
  bf16* ctx = xb;                    // alias: xb dead after V projection
  float* hbuf = (float*)d_out;       // fp32 scratch = output slot 0 (in-place LN)
  float* out2 = (float*)d_out + (size_t)MTOT * DMODEL;

  for (int l = 0; l < 4; ++l)
    prep_weff_kernel<<<dim3(DMODEL), dim3(256), 0, stream>>>(
        w_[l], A_[l], Bm_[l], weff + (size_t)l * DMODEL * DMODEL);
  cast_x_kernel<<<dim3(MTOT * DMODEL / 1024), dim3(256), 0, stream>>>(x, xb);

  dim3 gg(DMODEL / 128, MTOT / 128);
  gemm_kernel<0><<<gg, 256, 0, stream>>>(xb, weff,                         b_[0], Qb, nullptr, nullptr);
  gemm_kernel<0><<<gg, 256, 0, stream>>>(xb, weff + 1 * DMODEL * DMODEL,   b_[1], Kb, nullptr, nullptr);
  gemm_kernel<2><<<gg, 256, 0, stream>>>(xb, weff + 2 * DMODEL * DMODEL,   b_[2], Vt, nullptr, nullptr);

  flash_kernel<<<dim3(SEQ / 64, BATCH * NHEADS), 256, 0, stream>>>(Qb, Kb, Vt, ctx, mstat, lstat);
  mean_kernel<<<dim3(SEQ / 64, SEQ / 64, BATCH), 256, 0, stream>>>(Qb, Kb, mstat, lstat, out2);
  gemm_kernel<3><<<gg, 256, 0, stream>>>(ctx, weff + 3 * DMODEL * DMODEL,  b_[3], nullptr, hbuf, x);
  ln_kernel<<<dim3(MTOT), 256, 0, stream>>>(hbuf, lng, lnb, hbuf);
}

// Round 3
// 175.706 us; speedup vs baseline: 1.3121x; 1.3121x over previous
//
#include <hip/hip_runtime.h>

#define DMODEL 1024
#define NHEADS 16
#define DHEAD  64
#define RANK   16
#define BATCH  4
#define SEQ    1024
#define MTOT   (BATCH*SEQ)   // 4096
#define QSCALE 0.18033688011112042f  // log2(e)/8 : folded into Q projection

typedef __bf16 bf16;
typedef __bf16 bf16x8 __attribute__((ext_vector_type(8)));
typedef __bf16 bf16x4 __attribute__((ext_vector_type(4)));
typedef float  f32x4  __attribute__((ext_vector_type(4)));

// Byte-offset swizzle for LDS tiles with 128B rows (16B granules).
__device__ __forceinline__ int swz128(int row, int byte_in_row) {
  int slot = byte_in_row >> 4;
  return row * 128 + (((slot ^ (row & 7)) << 4) | (byte_in_row & 15));
}

// async global->LDS, 16B per lane. lds ptr wave-uniform; HW adds lane*16.
__device__ __forceinline__ void gll16(const void* g, void* l) {
  __builtin_amdgcn_global_load_lds((const __attribute__((address_space(1))) unsigned int*)g,
                                   (__attribute__((address_space(3))) unsigned int*)l, 16, 0, 0);
}

// two ds_read_b64_tr_b16 with literal offsets (rule 18 fence applied by caller)
#define TRRD(lo, hi, base, o0, o1)                                   \
  asm volatile("ds_read_b64_tr_b16 %0, %2 offset:" #o0 "\n\t"        \
               "ds_read_b64_tr_b16 %1, %2 offset:" #o1               \
               : "=v"(lo), "=v"(hi) : "v"(base));

// ---------------- Weff = W + 2 * (A@B)^T  (stored [n][k], bf16) -------------
__global__ void prep_weff_kernel(
    const float* __restrict__ W0, const float* __restrict__ A0, const float* __restrict__ B0,
    const float* __restrict__ W1, const float* __restrict__ A1, const float* __restrict__ B1,
    const float* __restrict__ W2, const float* __restrict__ A2, const float* __restrict__ B2,
    const float* __restrict__ W3, const float* __restrict__ A3, const float* __restrict__ B3,
    bf16* __restrict__ out) {
  const int l = blockIdx.y;
  const float* W = l == 0 ? W0 : l == 1 ? W1 : l == 2 ? W2 : W3;
  const float* A = l == 0 ? A0 : l == 1 ? A1 : l == 2 ? A2 : A3;
  const float* Bm = l == 0 ? B0 : l == 1 ? B1 : l == 2 ? B2 : B3;
  out += (size_t)l * DMODEL * DMODEL;
  const int n = blockIdx.x;
  __shared__ float bsc[RANK];
  if (threadIdx.x < RANK) bsc[threadIdx.x] = Bm[threadIdx.x * DMODEL + n] * 2.0f;
  __syncthreads();
  float br[RANK];
#pragma unroll
  for (int r = 0; r < RANK; ++r) br[r] = bsc[r];
  for (int k0 = 0; k0 < DMODEL; k0 += 256) {
    int k = k0 + threadIdx.x;
    float acc = W[n * DMODEL + k];
    const float4* arow = (const float4*)(A + k * RANK);
#pragma unroll
    for (int r4 = 0; r4 < 4; ++r4) {
      float4 a = arow[r4];
      acc += a.x*br[r4*4+0] + a.y*br[r4*4+1] + a.z*br[r4*4+2] + a.w*br[r4*4+3];
    }
    out[n * DMODEL + k] = (bf16)acc;
  }
}

__global__ void cast_x_kernel(const float* __restrict__ x, bf16* __restrict__ xb) {
  int i = (blockIdx.x * blockDim.x + threadIdx.x) * 4;
  float4 v = *(const float4*)(x + i);
  bf16x4 o = { (bf16)v.x, (bf16)v.y, (bf16)v.z, (bf16)v.w };
  *(bf16x4*)(xb + i) = o;
}

// ---------------- GEMM core: acc = A[m][k] dot B[n][k], GLL staging ---------
__device__ __forceinline__ void gemm_core(
    const bf16* __restrict__ Ain, const bf16* __restrict__ Bin,
    char* sA, char* sB, int m0, int n0, f32x4 (&acc)[4][4]) {
  const int tid = threadIdx.x;
  const int w = tid >> 6, lane = tid & 63;
  const int wm = (w & 1) * 64, wn = (w >> 1) * 64;
  // per-wave GLL source pointers (linear LDS dest, inverse-swizzled source)
  const bf16* pA[4]; const bf16* pB[4]; char* lA[4]; char* lB[4];
#pragma unroll
  for (int i = 0; i < 4; ++i) {
    int chunk = i * 4 + w;                // 16 x 1KB chunks per buffer
    int row = chunk * 8 + (lane >> 3);
    int ss = (lane & 7) ^ (row & 7);      // pre-swizzled source slot
    pA[i] = Ain + (size_t)(m0 + row) * DMODEL + ss * 8;
    pB[i] = Bin + (size_t)(n0 + row) * DMODEL + ss * 8;
    lA[i] = sA + chunk * 1024;
    lB[i] = sB + chunk * 1024;
  }
  for (int kt = 0; kt < DMODEL / 64; ++kt) {
    const int kbase = kt * 64;
#pragma unroll
    for (int i = 0; i < 4; ++i) {
      gll16(pA[i] + kbase, lA[i]);
      gll16(pB[i] + kbase, lB[i]);
    }
    __syncthreads();
#pragma unroll
    for (int ks = 0; ks < 2; ++ks) {
      bf16x8 af[4], bfg[4];
#pragma unroll
      for (int mi = 0; mi < 4; ++mi)
        af[mi] = *(const bf16x8*)(sA + swz128(wm + mi*16 + (lane & 15), ks*64 + (lane >> 4)*16));
#pragma unroll
      for (int ni = 0; ni < 4; ++ni)
        bfg[ni] = *(const bf16x8*)(sB + swz128(wn + ni*16 + (lane & 15), ks*64 + (lane >> 4)*16));
#pragma unroll
      for (int mi = 0; mi < 4; ++mi)
#pragma unroll
        for (int ni = 0; ni < 4; ++ni)
          acc[mi][ni] = __builtin_amdgcn_mfma_f32_16x16x32_bf16(af[mi], bfg[ni], acc[mi][ni], 0, 0, 0);
    }
    __syncthreads();
  }
}

// QKV fused: z=0 -> Q (scaled by log2e/8) [b][h][s][d]; z=1 -> K same; z=2 -> V^T [bh*64+d][s]
__global__ __launch_bounds__(256) void gemm_qkv_kernel(
    const bf16* __restrict__ xb, const bf16* __restrict__ weff,
    const float* __restrict__ bq, const float* __restrict__ bk, const float* __restrict__ bv,
    bf16* __restrict__ Qb, bf16* __restrict__ Kb, bf16* __restrict__ Vt)
{
  __shared__ __align__(16) char sA[128 * 128];
  __shared__ __align__(16) char sB[128 * 128];
  const int z = blockIdx.z;
  const bf16* Bin = weff + (size_t)z * DMODEL * DMODEL;
  const float* bias = z == 0 ? bq : z == 1 ? bk : bv;
  const int tid = threadIdx.x, w = tid >> 6, lane = tid & 63;
  const int m0 = blockIdx.y * 128, n0 = blockIdx.x * 128;
  const int wm = (w & 1) * 64, wn = (w >> 1) * 64;
  f32x4 acc[4][4] = {};
  gemm_core(xb, Bin, sA, sB, m0, n0, acc);
#pragma unroll
  for (int mi = 0; mi < 4; ++mi) {
#pragma unroll
    for (int ni = 0; ni < 4; ++ni) {
      int col = n0 + wn + ni * 16 + (lane & 15);
      float bcol = bias[col];
      int h = col >> 6, d = col & 63;
#pragma unroll
      for (int r = 0; r < 4; ++r) {
        int row = m0 + wm + mi * 16 + (lane >> 4) * 4 + r;
        float v = acc[mi][ni][r] + bcol;
        int b = row >> 10, s = row & 1023;
        if (z == 0)
          Qb[(size_t)((b * NHEADS + h) * SEQ + s) * DHEAD + d] = (bf16)(v * QSCALE);
        else if (z == 1)
          Kb[(size_t)((b * NHEADS + h) * SEQ + s) * DHEAD + d] = (bf16)v;
        else
          Vt[(size_t)((b * NHEADS + h) * DHEAD + d) * SEQ + s] = (bf16)v;
      }
    }
  }
}

// O projection + residual -> fp32
__global__ __launch_bounds__(256) void gemm_o_kernel(
    const bf16* __restrict__ ctx, const bf16* __restrict__ weff,
    const float* __restrict__ bias, const float* __restrict__ resid,
    float* __restrict__ outf)
{
  __shared__ __align__(16) char sA[128 * 128];
  __shared__ __align__(16) char sB[128 * 128];
  const int tid = threadIdx.x, w = tid >> 6, lane = tid & 63;
  const int m0 = blockIdx.y * 128, n0 = blockIdx.x * 128;
  const int wm = (w & 1) * 64, wn = (w >> 1) * 64;
  f32x4 acc[4][4] = {};
  gemm_core(ctx, weff, sA, sB, m0, n0, acc);
#pragma unroll
  for (int mi = 0; mi < 4; ++mi) {
#pragma unroll
    for (int ni = 0; ni < 4; ++ni) {
      int col = n0 + wn + ni * 16 + (lane & 15);
      float bcol = bias[col];
#pragma unroll
      for (int r = 0; r < 4; ++r) {
        int row = m0 + wm + mi * 16 + (lane >> 4) * 4 + r;
        outf[(size_t)row * DMODEL + col] =
            acc[mi][ni][r] + bcol + resid[(size_t)row * DMODEL + col];
      }
    }
  }
}

// ---------------- flash attention, no-max softmax (exp2, Q pre-scaled) ------
__global__ __launch_bounds__(256) void flash_kernel(
    const bf16* __restrict__ Qb, const bf16* __restrict__ Kb, const bf16* __restrict__ Vt,
    bf16* __restrict__ ctx, float* __restrict__ lstat)
{
  __shared__ __align__(16) char sK[64 * 128];   // rows=key, cols=d
  __shared__ __align__(16) char sV[64 * 128];   // rows=d,   cols=key
  __shared__ __align__(16) char sP[4 * 2048];   // per-wave P^T [64 key][16 q]
  const int tid = threadIdx.x, w = tid >> 6, lane = tid & 63;
  const int bh = blockIdx.y;
  const int q0 = blockIdx.x * 64;
  const bf16* Qbase = Qb + (size_t)bh * SEQ * DHEAD;
  const bf16* Kbase = Kb + (size_t)bh * SEQ * DHEAD;
  const bf16* Vbase = Vt + (size_t)bh * DHEAD * SEQ;
  const int qw = q0 + w * 16;

  bf16x8 aq[2];
#pragma unroll
  for (int ks = 0; ks < 2; ++ks)
    aq[ks] = *(const bf16x8*)(Qbase + (size_t)(qw + (lane & 15)) * DHEAD + ks * 32 + (lane >> 4) * 8);

  // GLL staging pointers (8 x 1KB chunks per buffer, 2 per wave)
  const bf16* pK[2]; const bf16* pV[2]; char* lK[2]; char* lV[2];
#pragma unroll
  for (int i = 0; i < 2; ++i) {
    int chunk = i * 4 + w;
    int row = chunk * 8 + (lane >> 3);
    int ss = (lane & 7) ^ (row & 7);
    pK[i] = Kbase + (size_t)row * DHEAD + ss * 8;   // + k0*DHEAD
    pV[i] = Vbase + (size_t)row * SEQ + ss * 8;     // + k0
    lK[i] = sK + chunk * 1024;
    lV[i] = sV + chunk * 1024;
  }

  char* sPw = sP + w * 2048;
  // ds_read_b64_tr_b16: each lane fetches 8B at its OWN addr; HW transposes
  // within 16-lane groups over the 128B region the group tiles. Group g owns
  // P^T key-rows g*8..g*8+7 (= 256B); lane-in-group tiles it naturally.
  const unsigned pbase = (unsigned)(uintptr_t)sPw + ((lane >> 4) << 8) + ((lane & 15) << 3);
  char* pwr = sPw + ((lane >> 4) << 3) + (lane & 15) * 32;

  f32x4 cacc[4] = {};
  float lsum[4] = {0.f, 0.f, 0.f, 0.f};

  for (int kt = 0; kt < SEQ / 64; ++kt) {
    const int k0 = kt * 64;
#pragma unroll
    for (int i = 0; i < 2; ++i) {
      gll16(pK[i] + (size_t)k0 * DHEAD, lK[i]);
      gll16(pV[i] + k0, lV[i]);
    }
    __syncthreads();

    f32x4 sc[4] = {};
#pragma unroll
    for (int ks = 0; ks < 2; ++ks)
#pragma unroll
      for (int ni = 0; ni < 4; ++ni) {
        bf16x8 bk = *(const bf16x8*)(sK + swz128(ni*16 + (lane & 15), ks*64 + (lane >> 4)*16));
        sc[ni] = __builtin_amdgcn_mfma_f32_16x16x32_bf16(aq[ks], bk, sc[ni], 0, 0, 0);
      }

    // P = exp2(sc) (Q pre-scaled by log2e/8); accumulate row partial sums;
    // write P^T [key][q]: per lane 4 consecutive q at fixed key -> b64 store
#pragma unroll
    for (int ni = 0; ni < 4; ++ni) {
      float p0 = __builtin_amdgcn_exp2f(sc[ni][0]);
      float p1 = __builtin_amdgcn_exp2f(sc[ni][1]);
      float p2 = __builtin_amdgcn_exp2f(sc[ni][2]);
      float p3 = __builtin_amdgcn_exp2f(sc[ni][3]);
      lsum[0] += p0; lsum[1] += p1; lsum[2] += p2; lsum[3] += p3;
      bf16x4 pb = { (bf16)p0, (bf16)p1, (bf16)p2, (bf16)p3 };
      *(bf16x4*)(pwr + ni * 512) = pb;   // key=ni*16+(lane&15) -> *32B
    }
    asm volatile("s_waitcnt lgkmcnt(0)" ::: "memory");

#pragma unroll
    for (int ks = 0; ks < 2; ++ks) {
      unsigned long long t0, t1;
      if (ks == 0) { TRRD(t0, t1, pbase, 0, 128) }
      else         { TRRD(t0, t1, pbase, 1024, 1152) }
      asm volatile("s_waitcnt lgkmcnt(0)" ::: "memory");
      __builtin_amdgcn_sched_barrier(0);
      union { unsigned long long u[2]; bf16x8 v; } pu;
      pu.u[0] = t0; pu.u[1] = t1;
#pragma unroll
      for (int ni = 0; ni < 4; ++ni) {
        bf16x8 bv = *(const bf16x8*)(sV + swz128(ni*16 + (lane & 15), ks*64 + (lane >> 4)*16));
        cacc[ni] = __builtin_amdgcn_mfma_f32_16x16x32_bf16(pu.v, bv, cacc[ni], 0, 0, 0);
      }
    }
    __syncthreads();
  }

  // one deferred row-sum reduce over the 16-lane group
#pragma unroll
  for (int r = 0; r < 4; ++r) {
#pragma unroll
    for (int off = 1; off < 16; off <<= 1) lsum[r] += __shfl_xor(lsum[r], off);
  }

  const int b = bh >> 4, hh = bh & 15;
#pragma unroll
  for (int r = 0; r < 4; ++r) {
    float inv = __builtin_amdgcn_rcpf(lsum[r]);
    int qrow = qw + (lane >> 4) * 4 + r;
#pragma unroll
    for (int ni = 0; ni < 4; ++ni) {
      int d = ni * 16 + (lane & 15);
      ctx[(size_t)(b * SEQ + qrow) * DMODEL + hh * DHEAD + d] = (bf16)(cacc[ni][r] * inv);
    }
    if ((lane & 15) == 0) lstat[(size_t)bh * SEQ + qrow] = lsum[r];
  }
}

// ---------------- attn.mean over heads: recompute scores, no max ------------
__global__ __launch_bounds__(256) void mean_kernel(
    const bf16* __restrict__ Qb, const bf16* __restrict__ Kb,
    const float* __restrict__ lstat, float* __restrict__ out2)
{
  __shared__ __align__(16) char sK[64 * 128];
  const int tid = threadIdx.x, w = tid >> 6, lane = tid & 63;
  const int b = blockIdx.z;
  const int q0 = blockIdx.x * 64, k0 = blockIdx.y * 64;
  const int qw = q0 + w * 16;
  // GLL chunk geometry (shared across heads)
  int chunk0 = 0 * 4 + w, chunk1 = 1 * 4 + w;
  int row0 = chunk0 * 8 + (lane >> 3), row1 = chunk1 * 8 + (lane >> 3);
  int ss0 = (lane & 7) ^ (row0 & 7), ss1 = (lane & 7) ^ (row1 & 7);
  char* lK0 = sK + chunk0 * 1024; char* lK1 = sK + chunk1 * 1024;
  f32x4 macc[4] = {};
  for (int h = 0; h < NHEADS; ++h) {
    int bh = b * NHEADS + h;
    const bf16* Qbase = Qb + (size_t)bh * SEQ * DHEAD;
    const bf16* Kbase = Kb + (size_t)bh * SEQ * DHEAD;
    gll16(Kbase + (size_t)(k0 + row0) * DHEAD + ss0 * 8, lK0);
    gll16(Kbase + (size_t)(k0 + row1) * DHEAD + ss1 * 8, lK1);
    __syncthreads();
    bf16x8 aq0 = *(const bf16x8*)(Qbase + (size_t)(qw + (lane & 15)) * DHEAD + (lane >> 4) * 8);
    bf16x8 aq1 = *(const bf16x8*)(Qbase + (size_t)(qw + (lane & 15)) * DHEAD + 32 + (lane >> 4) * 8);
    f32x4 sc[4] = {};
#pragma unroll
    for (int ni = 0; ni < 4; ++ni) {
      bf16x8 bk0 = *(const bf16x8*)(sK + swz128(ni*16 + (lane & 15), (lane >> 4)*16));
      sc[ni] = __builtin_amdgcn_mfma_f32_16x16x32_bf16(aq0, bk0, sc[ni], 0, 0, 0);
      bf16x8 bk1 = *(const bf16x8*)(sK + swz128(ni*16 + (lane & 15), 64 + (lane >> 4)*16));
      sc[ni] = __builtin_amdgcn_mfma_f32_16x16x32_bf16(aq1, bk1, sc[ni], 0, 0, 0);
    }
    float lsc[4];
#pragma unroll
    for (int r = 0; r < 4; ++r) {
      int qrow = qw + (lane >> 4) * 4 + r;
      lsc[r] = 0.0625f * __builtin_amdgcn_rcpf(lstat[(size_t)bh * SEQ + qrow]);
    }
#pragma unroll
    for (int ni = 0; ni < 4; ++ni)
#pragma unroll
      for (int r = 0; r < 4; ++r)
        macc[ni][r] += __builtin_amdgcn_exp2f(sc[ni][r]) * lsc[r];
    __syncthreads();
  }
#pragma unroll
  for (int r = 0; r < 4; ++r) {
    int qrow = qw + (lane >> 4) * 4 + r;
#pragma unroll
    for (int ni = 0; ni < 4; ++ni)
      out2[(size_t)(b * SEQ + qrow) * SEQ + k0 + ni * 16 + (lane & 15)] = macc[ni][r];
  }
}

// ---------------- residual LayerNorm (in-place on fp32 rows) ----------------
__global__ __launch_bounds__(256) void ln_kernel(
    float* __restrict__ hb, const float* __restrict__ g,
    const float* __restrict__ bvec, float* __restrict__ out)
{
  const int row = blockIdx.x, t = threadIdx.x;
  float4 v = *(const float4*)(hb + (size_t)row * DMODEL + t * 4);
  float s = v.x + v.y + v.z + v.w;
  float s2 = v.x*v.x + v.y*v.y + v.z*v.z + v.w*v.w;
#pragma unroll
  for (int off = 32; off >= 1; off >>= 1) {
    s  += __shfl_down(s, off);
    s2 += __shfl_down(s2, off);
  }
  __shared__ float red[8];
  const int w = t >> 6;
  if ((t & 63) == 0) { red[w] = s; red[4 + w] = s2; }
  __syncthreads();
  if (t == 0) {
    red[0] = red[0] + red[1] + red[2] + red[3];
    red[4] = red[4] + red[5] + red[6] + red[7];
  }
  __syncthreads();
  float mu = red[0] * (1.0f / DMODEL);
  float var = red[4] * (1.0f / DMODEL) - mu * mu;
  float rs = rsqrtf(var + 1e-5f);
  float4 gv = *(const float4*)(g + t * 4);
  float4 bv = *(const float4*)(bvec + t * 4);
  float4 o;
  o.x = (v.x - mu) * rs * gv.x + bv.x;
  o.y = (v.y - mu) * rs * gv.y + bv.y;
  o.z = (v.z - mu) * rs * gv.z + bv.z;
  o.w = (v.w - mu) * rs * gv.w + bv.w;
  *(float4*)(out + (size_t)row * DMODEL + t * 4) = o;
}

extern "C" void kernel_launch(void* const* d_in, const int* in_sizes, int n_in,
                              void* d_out, int out_size, void* d_ws, size_t ws_size,
                              hipStream_t stream) {
  (void)in_sizes; (void)n_in; (void)out_size; (void)ws_size;
  const float* x = (const float*)d_in[0];
  const float* w_[4]  = {(const float*)d_in[1],  (const float*)d_in[5],
                         (const float*)d_in[9],  (const float*)d_in[13]};
  const float* b_[4]  = {(const float*)d_in[2],  (const float*)d_in[6],
                         (const float*)d_in[10], (const float*)d_in[14]};
  const float* A_[4]  = {(const float*)d_in[3],  (const float*)d_in[7],
                         (const float*)d_in[11], (const float*)d_in[15]};
  const float* Bm_[4] = {(const float*)d_in[4],  (const float*)d_in[8],
                         (const float*)d_in[12], (const float*)d_in[16]};
  const float* lng = (const float*)d_in[17];
  const float* lnb = (const float*)d_in[18];

  char* ws = (char*)d_ws;
  bf16* xb    = (bf16*)(ws);                         // 8MB, reused as ctx later
  bf16* weff  = (bf16*)(ws + (8u  << 20));           // 4 x 2MB
  bf16* Qb    = (bf16*)(ws + (16u << 20));           // 8MB [b][h][s][d] (pre-scaled)
  bf16* Kb    = (bf16*)(ws + (24u << 20));           // 8MB [b][h][s][d]
  bf16* Vt    = (bf16*)(ws + (32u << 20));           // 8MB [b][h][d][s]
  float* lstat = (float*)(ws + (40u << 20));         // 256KB
  bf16* ctx = xb;                    // alias: xb dead after QKV projections
  float* hbuf = (float*)d_out;       // fp32 scratch = output slot 0 (in-place LN)
  float* out2 = (float*)d_out + (size_t)MTOT * DMODEL;

  prep_weff_kernel<<<dim3(DMODEL, 4), dim3(256), 0, stream>>>(
      w_[0], A_[0], Bm_[0], w_[1], A_[1], Bm_[1],
      w_[2], A_[2], Bm_[2], w_[3], A_[3], Bm_[3], weff);
  cast_x_kernel<<<dim3(MTOT * DMODEL / 1024), dim3(256), 0, stream>>>(x, xb);

  gemm_qkv_kernel<<<dim3(DMODEL / 128, MTOT / 128, 3), 256, 0, stream>>>(
      xb, weff, b_[0], b_[1], b_[2], Qb, Kb, Vt);

  flash_kernel<<<dim3(SEQ / 64, BATCH * NHEADS), 256, 0, stream>>>(Qb, Kb, Vt, ctx, lstat);
  mean_kernel<<<dim3(SEQ / 64, SEQ / 64, BATCH), 256, 0, stream>>>(Qb, Kb, lstat, out2);
  gemm_o_kernel<<<dim3(DMODEL / 128, MTOT / 128), 256, 0, stream>>>(
      ctx, weff + 3u * DMODEL * DMODEL, b_[3], x, hbuf);
  ln_kernel<<<dim3(MTOT), 256, 0, stream>>>(hbuf, lng, lnb, hbuf);
}